// Round 3
// baseline (286.709 us; speedup 1.0000x reference)
//
#include <hip/hip_runtime.h>

#define N_NODES 16384
#define N_EDGES 262144
#define D 256
#define B_GRAPHS 32
#define NODES_PER_GRAPH 512   // N_NODES / B_GRAPHS

typedef unsigned short u16;
typedef __attribute__((ext_vector_type(8)))  short bf16x8;
typedef __attribute__((ext_vector_type(16))) float f32x16;
typedef __attribute__((ext_vector_type(8)))  unsigned short u16x8;
typedef __attribute__((ext_vector_type(4)))  unsigned short u16x4;

static __device__ __forceinline__ u16 f2bf(float f) {
    unsigned int u = __float_as_uint(f);
    unsigned int r = (u + 0x7FFFu + ((u >> 16) & 1u)) >> 16;   // RNE
    return (u16)r;
}
static __device__ __forceinline__ float bf2f(u16 h) {
    return __uint_as_float(((unsigned int)h) << 16);
}
// involution swizzle on byte offsets within an 8KB [128 rows x 64B] LDS array:
// XOR bits 4-5 with bits 7-8 (row bits 1-2). Bits 7-8 untouched -> involution.
static __device__ __forceinline__ int swz(int a) {
    return a ^ (((a >> 7) & 3) << 4);
}
static __device__ __forceinline__ void gload16(const void* g, void* l) {
    __builtin_amdgcn_global_load_lds(
        (const __attribute__((address_space(1))) unsigned int*)g,
        (__attribute__((address_space(3))) unsigned int*)l, 16, 0, 0);
}

// ---------------------------------------------------------------------------
// CSR build
// ---------------------------------------------------------------------------
__global__ __launch_bounds__(256) void zero_deg_kernel(int* __restrict__ deg) {
    deg[blockIdx.x * 256 + threadIdx.x] = 0;
}

__global__ __launch_bounds__(256) void count_deg_kernel(const int* __restrict__ edge,
                                                        int* __restrict__ deg) {
    int e = blockIdx.x * 256 + threadIdx.x;
    if (e < N_EDGES) atomicAdd(&deg[edge[N_EDGES + e]], 1);
}

__global__ __launch_bounds__(256) void scan_kernel(const int* __restrict__ deg,
                                                   int* __restrict__ row_ptr,
                                                   int* __restrict__ cursor,
                                                   float* __restrict__ inv_deg) {
    int t = threadIdx.x;
    int base = t * 64;
    int s = 0;
    for (int i = 0; i < 64; ++i) s += deg[base + i];
    __shared__ int sums[256];
    sums[t] = s;
    __syncthreads();
    for (int off = 1; off < 256; off <<= 1) {
        int v = (t >= off) ? sums[t - off] : 0;
        __syncthreads();
        sums[t] += v;
        __syncthreads();
    }
    int prefix = (t == 0) ? 0 : sums[t - 1];
    for (int i = 0; i < 64; ++i) {
        int d = deg[base + i];
        row_ptr[base + i] = prefix;
        cursor[base + i]  = prefix;
        inv_deg[base + i] = 1.0f / (float)(d < 1 ? 1 : d);
        prefix += d;
    }
    if (t == 255) row_ptr[N_NODES] = prefix;
}

__global__ __launch_bounds__(256) void fill_kernel(const int* __restrict__ edge,
                                                   int* __restrict__ cursor,
                                                   int* __restrict__ col) {
    int e = blockIdx.x * 256 + threadIdx.x;
    if (e < N_EDGES) {
        int pos = atomicAdd(&cursor[edge[N_EDGES + e]], 1);
        col[pos] = edge[e];
    }
}

// ---------------------------------------------------------------------------
// split_x: f32 -> (hi, lo) bf16 arrays
// ---------------------------------------------------------------------------
__global__ __launch_bounds__(256) void split_x_kernel(const float* __restrict__ x,
                                                      u16* __restrict__ hi,
                                                      u16* __restrict__ lo) {
    size_t e0 = ((size_t)blockIdx.x * 256 + threadIdx.x) * 8;
    float4 v0 = *(const float4*)&x[e0];
    float4 v1 = *(const float4*)&x[e0 + 4];
    float xs[8] = {v0.x, v0.y, v0.z, v0.w, v1.x, v1.y, v1.z, v1.w};
    u16x8 H, L;
    #pragma unroll
    for (int j = 0; j < 8; ++j) {
        u16 h = f2bf(xs[j]);
        H[j] = h; L[j] = f2bf(xs[j] - bf2f(h));
    }
    *(u16x8*)&hi[e0] = H;
    *(u16x8*)&lo[e0] = L;
}

// ---------------------------------------------------------------------------
// Mean aggregation: one wave per node; gathers HI ONLY (halves L3 traffic);
// fp32 accumulate; writes split hi/lo.
// ---------------------------------------------------------------------------
__global__ __launch_bounds__(256) void agg_kernel(const u16* __restrict__ Xhi,
                                                  const int* __restrict__ row_ptr,
                                                  const int* __restrict__ col,
                                                  const float* __restrict__ inv_deg,
                                                  u16* __restrict__ Agghi,
                                                  u16* __restrict__ Agglo) {
    int node = blockIdx.x * 4 + (threadIdx.x >> 6);
    int lane = threadIdx.x & 63;
    int start = row_ptr[node];
    int end   = row_ptr[node + 1];
    float a0 = 0.f, a1 = 0.f, a2 = 0.f, a3 = 0.f;
    for (int e0 = start; e0 < end; e0 += 64) {
        int cnt = end - e0; if (cnt > 64) cnt = 64;
        int my = (lane < cnt) ? col[e0 + lane] : 0;
        for (int j = 0; j < cnt; ++j) {
            int s = __shfl(my, j);
            u16x4 v = *(const u16x4*)&Xhi[(size_t)s * D + lane * 4];
            a0 += bf2f(v[0]); a1 += bf2f(v[1]); a2 += bf2f(v[2]); a3 += bf2f(v[3]);
        }
    }
    float id = inv_deg[node];
    float m[4] = {a0 * id, a1 * id, a2 * id, a3 * id};
    u16x4 H, L;
    #pragma unroll
    for (int j = 0; j < 4; ++j) {
        u16 h = f2bf(m[j]);
        H[j] = h; L[j] = f2bf(m[j] - bf2f(h));
    }
    *(u16x4*)&Agghi[(size_t)node * D + lane * 4] = H;
    *(u16x4*)&Agglo[(size_t)node * D + lane * 4] = L;
}

// ---------------------------------------------------------------------------
// W pre-transpose + split: Wt_hi[n][k], Wt_lo[n][k] (bf16) from W[k][n] f32.
// ---------------------------------------------------------------------------
__global__ __launch_bounds__(256) void transpose_w_kernel(
    const float* __restrict__ Wl, const float* __restrict__ Wr,
    u16* __restrict__ WtL_hi, u16* __restrict__ WtL_lo,
    u16* __restrict__ WtR_hi, u16* __restrict__ WtR_lo)
{
    __shared__ float S[64][68];
    int bid = blockIdx.x;
    int mat = bid / 16, sub = bid % 16;
    int kt = (sub >> 2) * 64, nt = (sub & 3) * 64;
    const float* src = (mat < 3) ? Wl + (size_t)mat * 65536 : Wr + (size_t)(mat - 3) * 65536;
    u16* dhi = (mat < 3) ? WtL_hi + (size_t)mat * 65536 : WtR_hi + (size_t)(mat - 3) * 65536;
    u16* dlo = (mat < 3) ? WtL_lo + (size_t)mat * 65536 : WtR_lo + (size_t)(mat - 3) * 65536;
    int t = threadIdx.x;
    int r = t >> 2, c0 = (t & 3) * 16;
    #pragma unroll
    for (int j = 0; j < 4; ++j) {
        float4 v = *(const float4*)&src[(size_t)(kt + r) * 256 + nt + c0 + j * 4];
        *(float4*)&S[r][c0 + j * 4] = v;
    }
    __syncthreads();
    int n = t >> 2, kc = (t & 3) * 16;
    u16x8 h0, h1, l0, l1;
    #pragma unroll
    for (int j = 0; j < 8; ++j) {
        float x = S[kc + j][n];
        u16 h = f2bf(x);
        h0[j] = h; l0[j] = f2bf(x - bf2f(h));
        float y = S[kc + 8 + j][n];
        u16 g = f2bf(y);
        h1[j] = g; l1[j] = f2bf(y - bf2f(g));
    }
    size_t o = (size_t)(nt + n) * 256 + kt + kc;
    *(u16x8*)&dhi[o] = h0; *(u16x8*)&dhi[o + 8] = h1;
    *(u16x8*)&dlo[o] = l0; *(u16x8*)&dlo[o + 8] = l1;
}

// ---------------------------------------------------------------------------
// MFMA dual GEMM, split-bf16 3-pass, pre-split operands, global_load_lds
// staging with swizzled source, double-buffered LDS, 2-phase schedule.
// Block 128x128, 4 waves (2x2), wave tile 64x64 (2x2 frags of 32x32x16).
// ---------------------------------------------------------------------------
__global__ __launch_bounds__(256) void gemm_mfma_kernel(
    const u16* __restrict__ Xhi,   const u16* __restrict__ Xlo,
    const u16* __restrict__ Agghi, const u16* __restrict__ Agglo,
    const u16* __restrict__ WtRhi, const u16* __restrict__ WtRlo,
    const u16* __restrict__ WtLhi, const u16* __restrict__ WtLlo,
    const float* __restrict__ bias,
    u16* __restrict__ Xohi, u16* __restrict__ Xolo)
{
    // [buf][arr: Ahi,Alo,Bhi,Blo][8KB] ; 64 KiB total
    __shared__ u16 lds[2][4][4096];

    const int tid  = threadIdx.x;
    const int w    = tid >> 6, lane = tid & 63;
    const int wm   = w >> 1, wn = w & 1;
    const int bid  = blockIdx.x;
    const int m0   = (bid >> 1) * 128;
    const int n0   = (bid & 1) * 128;

    f32x16 acc[4];
    #pragma unroll
    for (int f = 0; f < 4; ++f)
        #pragma unroll
        for (int j = 0; j < 16; ++j) acc[f][j] = 0.f;

    const int r32 = lane & 31;
    const int khb = (lane >> 5) * 16;       // byte offset of 8-elem k-half

    auto stage = [&](int buf, int tt) {
        const u16* src; int rbase;
        const int k0 = (tt & 7) * 32;
        const bool ph2 = tt >= 8;
        if      (w == 0) { src = ph2 ? Agghi : Xhi;  rbase = m0; }
        else if (w == 1) { src = ph2 ? Agglo : Xlo;  rbase = m0; }
        else if (w == 2) { src = ph2 ? WtLhi : WtRhi; rbase = n0; }
        else             { src = ph2 ? WtLlo : WtRlo; rbase = n0; }
        char* base = (char*)&lds[buf][w][0];
        #pragma unroll
        for (int i = 0; i < 8; ++i) {
            int o = i * 1024 + lane * 16;   // physical byte offset
            int a = swz(o);                 // logical byte offset (involution)
            const u16* g = src + (size_t)(rbase + (a >> 6)) * D + k0 + ((a & 63) >> 1);
            gload16(g, base + i * 1024);
        }
    };

    auto compute = [&](int buf) {
        const char* Ah = (const char*)&lds[buf][0][0];
        const char* Al = (const char*)&lds[buf][1][0];
        const char* Bh = (const char*)&lds[buf][2][0];
        const char* Bl = (const char*)&lds[buf][3][0];
        #pragma unroll
        for (int s = 0; s < 2; ++s) {
            const int cb = s * 32 + khb;
            const int ra0 = wm * 64 + r32, ra1 = ra0 + 32;
            const int rb0 = wn * 64 + r32, rb1 = rb0 + 32;
            bf16x8 ah0 = *(const bf16x8*)(Ah + swz(ra0 * 64 + cb));
            bf16x8 ah1 = *(const bf16x8*)(Ah + swz(ra1 * 64 + cb));
            bf16x8 al0 = *(const bf16x8*)(Al + swz(ra0 * 64 + cb));
            bf16x8 al1 = *(const bf16x8*)(Al + swz(ra1 * 64 + cb));
            bf16x8 bh0 = *(const bf16x8*)(Bh + swz(rb0 * 64 + cb));
            bf16x8 bh1 = *(const bf16x8*)(Bh + swz(rb1 * 64 + cb));
            bf16x8 bl0 = *(const bf16x8*)(Bl + swz(rb0 * 64 + cb));
            bf16x8 bl1 = *(const bf16x8*)(Bl + swz(rb1 * 64 + cb));
            acc[0] = __builtin_amdgcn_mfma_f32_32x32x16_bf16(ah0, bh0, acc[0], 0, 0, 0);
            acc[1] = __builtin_amdgcn_mfma_f32_32x32x16_bf16(ah0, bh1, acc[1], 0, 0, 0);
            acc[2] = __builtin_amdgcn_mfma_f32_32x32x16_bf16(ah1, bh0, acc[2], 0, 0, 0);
            acc[3] = __builtin_amdgcn_mfma_f32_32x32x16_bf16(ah1, bh1, acc[3], 0, 0, 0);
            acc[0] = __builtin_amdgcn_mfma_f32_32x32x16_bf16(al0, bh0, acc[0], 0, 0, 0);
            acc[1] = __builtin_amdgcn_mfma_f32_32x32x16_bf16(al0, bh1, acc[1], 0, 0, 0);
            acc[2] = __builtin_amdgcn_mfma_f32_32x32x16_bf16(al1, bh0, acc[2], 0, 0, 0);
            acc[3] = __builtin_amdgcn_mfma_f32_32x32x16_bf16(al1, bh1, acc[3], 0, 0, 0);
            acc[0] = __builtin_amdgcn_mfma_f32_32x32x16_bf16(ah0, bl0, acc[0], 0, 0, 0);
            acc[1] = __builtin_amdgcn_mfma_f32_32x32x16_bf16(ah0, bl1, acc[1], 0, 0, 0);
            acc[2] = __builtin_amdgcn_mfma_f32_32x32x16_bf16(ah1, bl0, acc[2], 0, 0, 0);
            acc[3] = __builtin_amdgcn_mfma_f32_32x32x16_bf16(ah1, bl1, acc[3], 0, 0, 0);
        }
    };

    stage(0, 0);
    __syncthreads();
    int cur = 0;
    for (int t = 0; t < 16; ++t) {
        if (t < 15) stage(cur ^ 1, t + 1);
        compute(cur);
        __syncthreads();
        cur ^= 1;
    }

    // epilogue: C/D layout col=lane&31, row=(reg&3)+8*(reg>>2)+4*(lane>>5)
    #pragma unroll
    for (int fm = 0; fm < 2; ++fm) {
        #pragma unroll
        for (int fn = 0; fn < 2; ++fn) {
            const int colc = n0 + wn * 64 + fn * 32 + r32;
            const int rowb = m0 + wm * 64 + fm * 32 + 4 * (lane >> 5);
            const float bv = bias[colc];
            #pragma unroll
            for (int reg = 0; reg < 16; ++reg) {
                const int row = rowb + (reg & 3) + 8 * (reg >> 2);
                float v = acc[fm * 2 + fn][reg] + bv;
                u16 h = f2bf(v);
                Xohi[(size_t)row * D + colc] = h;
                Xolo[(size_t)row * D + colc] = f2bf(v - bf2f(h));
            }
        }
    }
}

// ---------------------------------------------------------------------------
// MLP head: single block, 1024 threads; 32 graphs x 3 chained GEMV layers.
// ---------------------------------------------------------------------------
__global__ __launch_bounds__(1024) void head_kernel(const u16* __restrict__ Xhi,
                                                    const u16* __restrict__ Xlo,
                                                    const float* __restrict__ Wh,
                                                    const float* __restrict__ bh,
                                                    const float* __restrict__ Wo,
                                                    const float* __restrict__ bo,
                                                    float* __restrict__ out) {
    __shared__ float h[B_GRAPHS][D];    // 32 KiB
    const int t = threadIdx.x;
    #pragma unroll
    for (int i = 0; i < 8; ++i) {
        int e = i * 1024 + t;
        int g = e >> 8, k = e & 255;
        size_t idx = (size_t)(g * NODES_PER_GRAPH) * D + k;
        h[g][k] = bf2f(Xhi[idx]) + bf2f(Xlo[idx]);
    }
    __syncthreads();
    const int c4  = t & 63;        // float4 column index (cols c4*4 .. +3)
    const int grp = t >> 6;        // graphs grp*2, grp*2+1
    for (int l = 0; l < 3; ++l) {
        const float* W  = (l < 2) ? Wh + (size_t)l * D * D : Wo;
        const float* bb = (l < 2) ? bh + (size_t)l * D : bo;
        float a0[4] = {0, 0, 0, 0}, a1[4] = {0, 0, 0, 0};
        #pragma unroll 4
        for (int k = 0; k < D; ++k) {
            float4 wv = *(const float4*)&W[(size_t)k * D + c4 * 4];
            float h0 = h[grp * 2][k], h1 = h[grp * 2 + 1][k];
            a0[0] += h0 * wv.x; a0[1] += h0 * wv.y; a0[2] += h0 * wv.z; a0[3] += h0 * wv.w;
            a1[0] += h1 * wv.x; a1[1] += h1 * wv.y; a1[2] += h1 * wv.z; a1[3] += h1 * wv.w;
        }
        __syncthreads();
        if (l < 2) {
            #pragma unroll
            for (int j = 0; j < 4; ++j) {
                float b = bb[c4 * 4 + j];
                h[grp * 2][c4 * 4 + j]     = fmaxf(a0[j] + b, 0.f);
                h[grp * 2 + 1][c4 * 4 + j] = fmaxf(a1[j] + b, 0.f);
            }
            __syncthreads();
        } else {
            #pragma unroll
            for (int j = 0; j < 4; ++j) {
                float b = bb[c4 * 4 + j];
                out[(size_t)(grp * 2) * D + c4 * 4 + j]     = a0[j] + b;
                out[(size_t)(grp * 2 + 1) * D + c4 * 4 + j] = a1[j] + b;
            }
        }
    }
}

// ---------------------------------------------------------------------------
extern "C" void kernel_launch(void* const* d_in, const int* in_sizes, int n_in,
                              void* d_out, int out_size, void* d_ws, size_t ws_size,
                              hipStream_t stream) {
    const float* x    = (const float*)d_in[0];
    const int*   edge = (const int*)d_in[1];
    const float* Wl   = (const float*)d_in[2];
    const float* bl   = (const float*)d_in[3];
    const float* Wr   = (const float*)d_in[4];
    const float* Wh   = (const float*)d_in[5];
    const float* bh   = (const float*)d_in[6];
    const float* Wo   = (const float*)d_in[7];
    const float* bo   = (const float*)d_in[8];
    float* out = (float*)d_out;

    char* w = (char*)d_ws;
    auto alloc = [&](size_t bytes) {
        char* p = w;
        w += (bytes + 255) & ~(size_t)255;
        return p;
    };
    int*   deg     = (int*)  alloc((size_t)N_NODES * 4);
    int*   row_ptr = (int*)  alloc((size_t)(N_NODES + 1) * 4);
    int*   cursor  = (int*)  alloc((size_t)N_NODES * 4);
    float* invdeg  = (float*)alloc((size_t)N_NODES * 4);
    int*   col     = (int*)  alloc((size_t)N_EDGES * 4);
    u16* Xh[2] = {(u16*)alloc((size_t)N_NODES * D * 2), (u16*)alloc((size_t)N_NODES * D * 2)};
    u16* Xl[2] = {(u16*)alloc((size_t)N_NODES * D * 2), (u16*)alloc((size_t)N_NODES * D * 2)};
    u16* Agghi = (u16*)alloc((size_t)N_NODES * D * 2);
    u16* Agglo = (u16*)alloc((size_t)N_NODES * D * 2);
    u16* WtLhi = (u16*)alloc((size_t)3 * 65536 * 2);
    u16* WtLlo = (u16*)alloc((size_t)3 * 65536 * 2);
    u16* WtRhi = (u16*)alloc((size_t)3 * 65536 * 2);
    u16* WtRlo = (u16*)alloc((size_t)3 * 65536 * 2);

    transpose_w_kernel<<<96, 256, 0, stream>>>(Wl, Wr, WtLhi, WtLlo, WtRhi, WtRlo);
    split_x_kernel<<<N_NODES * D / (256 * 8), 256, 0, stream>>>(x, Xh[0], Xl[0]);

    zero_deg_kernel<<<N_NODES / 256, 256, 0, stream>>>(deg);
    count_deg_kernel<<<N_EDGES / 256, 256, 0, stream>>>(edge, deg);
    scan_kernel<<<1, 256, 0, stream>>>(deg, row_ptr, cursor, invdeg);
    fill_kernel<<<N_EDGES / 256, 256, 0, stream>>>(edge, cursor, col);

    for (int l = 0; l < 3; ++l) {
        int in = l & 1, o = in ^ 1;   // 0:Xa->Xb, 1:Xb->Xa, 2:Xa->Xb
        agg_kernel<<<N_NODES / 4, 256, 0, stream>>>(Xh[in], row_ptr, col, invdeg,
                                                    Agghi, Agglo);
        gemm_mfma_kernel<<<256, 256, 0, stream>>>(
            Xh[in], Xl[in], Agghi, Agglo,
            WtRhi + (size_t)l * 65536, WtRlo + (size_t)l * 65536,
            WtLhi + (size_t)l * 65536, WtLlo + (size_t)l * 65536,
            bl + (size_t)l * D, Xh[o], Xl[o]);
    }
    head_kernel<<<1, 1024, 0, stream>>>(Xh[1], Xl[1], Wh, bh, Wo, bo, out);
}

// Round 4
// 204.984 us; speedup vs baseline: 1.3987x; 1.3987x over previous
//
#include <hip/hip_runtime.h>

#define N_NODES 16384
#define N_EDGES 262144
#define D 256
#define B_GRAPHS 32
#define NODES_PER_GRAPH 512   // N_NODES / B_GRAPHS

typedef unsigned short u16;
typedef __attribute__((ext_vector_type(8)))  short bf16x8;
typedef __attribute__((ext_vector_type(16))) float f32x16;
typedef __attribute__((ext_vector_type(8)))  unsigned short u16x8;
typedef __attribute__((ext_vector_type(4)))  unsigned short u16x4;

static __device__ __forceinline__ u16 f2bf(float f) {
    unsigned int u = __float_as_uint(f);
    unsigned int r = (u + 0x7FFFu + ((u >> 16) & 1u)) >> 16;   // RNE
    return (u16)r;
}
static __device__ __forceinline__ float bf2f(u16 h) {
    return __uint_as_float(((unsigned int)h) << 16);
}
// involution swizzle on byte offsets within an 8KB [128 rows x 64B] LDS array:
// XOR bits 4-5 with bits 7-8 (row bits 1-2). Rows 0-7 tile all 32 banks for
// consecutive-8-lane b128 groups -> conflict-free reads.
static __device__ __forceinline__ int swz(int a) {
    return a ^ (((a >> 7) & 3) << 4);
}
static __device__ __forceinline__ void gload16(const void* g, void* l) {
    __builtin_amdgcn_global_load_lds(
        (const __attribute__((address_space(1))) unsigned int*)g,
        (__attribute__((address_space(3))) unsigned int*)l, 16, 0, 0);
}

// ---------------------------------------------------------------------------
// prep: blocks [0,96) transpose+split W; [96,160) zero deg; [160,2208) split x
// ---------------------------------------------------------------------------
__global__ __launch_bounds__(256) void prep_kernel(
    const float* __restrict__ x, const float* __restrict__ Wl,
    const float* __restrict__ Wr,
    u16* __restrict__ Xhi, u16* __restrict__ Xlo,
    u16* __restrict__ WtL_hi, u16* __restrict__ WtL_lo,
    u16* __restrict__ WtR_hi, u16* __restrict__ WtR_lo,
    int* __restrict__ deg)
{
    __shared__ float S[64][68];
    const int bid = blockIdx.x;
    const int t = threadIdx.x;
    if (bid < 96) {
        int mat = bid / 16, sub = bid % 16;
        int kt = (sub >> 2) * 64, nt = (sub & 3) * 64;
        const float* src = (mat < 3) ? Wl + (size_t)mat * 65536 : Wr + (size_t)(mat - 3) * 65536;
        u16* dhi = (mat < 3) ? WtL_hi + (size_t)mat * 65536 : WtR_hi + (size_t)(mat - 3) * 65536;
        u16* dlo = (mat < 3) ? WtL_lo + (size_t)mat * 65536 : WtR_lo + (size_t)(mat - 3) * 65536;
        int r = t >> 2, c0 = (t & 3) * 16;
        #pragma unroll
        for (int j = 0; j < 4; ++j) {
            float4 v = *(const float4*)&src[(size_t)(kt + r) * 256 + nt + c0 + j * 4];
            *(float4*)&S[r][c0 + j * 4] = v;
        }
        __syncthreads();
        int n = t >> 2, kc = (t & 3) * 16;
        u16x8 h0, h1, l0, l1;
        #pragma unroll
        for (int j = 0; j < 8; ++j) {
            float xv = S[kc + j][n];
            u16 h = f2bf(xv);
            h0[j] = h; l0[j] = f2bf(xv - bf2f(h));
            float y = S[kc + 8 + j][n];
            u16 g = f2bf(y);
            h1[j] = g; l1[j] = f2bf(y - bf2f(g));
        }
        size_t o = (size_t)(nt + n) * 256 + kt + kc;
        *(u16x8*)&dhi[o] = h0; *(u16x8*)&dhi[o + 8] = h1;
        *(u16x8*)&dlo[o] = l0; *(u16x8*)&dlo[o + 8] = l1;
    } else if (bid < 160) {
        deg[(bid - 96) * 256 + t] = 0;
    } else {
        size_t e0 = ((size_t)(bid - 160) * 256 + t) * 8;
        float4 v0 = *(const float4*)&x[e0];
        float4 v1 = *(const float4*)&x[e0 + 4];
        float xs[8] = {v0.x, v0.y, v0.z, v0.w, v1.x, v1.y, v1.z, v1.w};
        u16x8 H, L;
        #pragma unroll
        for (int j = 0; j < 8; ++j) {
            u16 h = f2bf(xs[j]);
            H[j] = h; L[j] = f2bf(xs[j] - bf2f(h));
        }
        *(u16x8*)&Xhi[e0] = H;
        *(u16x8*)&Xlo[e0] = L;
    }
}

// ---------------------------------------------------------------------------
// CSR build
// ---------------------------------------------------------------------------
__global__ __launch_bounds__(256) void count_deg_kernel(const int* __restrict__ edge,
                                                        int* __restrict__ deg) {
    int e = blockIdx.x * 256 + threadIdx.x;
    if (e < N_EDGES) atomicAdd(&deg[edge[N_EDGES + e]], 1);
}

__global__ __launch_bounds__(256) void scan_kernel(const int* __restrict__ deg,
                                                   int* __restrict__ row_ptr,
                                                   int* __restrict__ cursor,
                                                   float* __restrict__ inv_deg) {
    int t = threadIdx.x;
    int base = t * 64;
    int s = 0;
    #pragma unroll
    for (int i = 0; i < 16; ++i) {
        int4 v = *(const int4*)&deg[base + i * 4];
        s += v.x + v.y + v.z + v.w;
    }
    __shared__ int sums[256];
    sums[t] = s;
    __syncthreads();
    for (int off = 1; off < 256; off <<= 1) {
        int v = (t >= off) ? sums[t - off] : 0;
        __syncthreads();
        sums[t] += v;
        __syncthreads();
    }
    int prefix = (t == 0) ? 0 : sums[t - 1];
    #pragma unroll
    for (int i = 0; i < 16; ++i) {
        int4 d = *(const int4*)&deg[base + i * 4];
        int4 rp;
        rp.x = prefix;
        rp.y = rp.x + d.x;
        rp.z = rp.y + d.y;
        rp.w = rp.z + d.z;
        *(int4*)&row_ptr[base + i * 4] = rp;
        *(int4*)&cursor[base + i * 4]  = rp;
        float4 iv;
        iv.x = 1.0f / (float)(d.x < 1 ? 1 : d.x);
        iv.y = 1.0f / (float)(d.y < 1 ? 1 : d.y);
        iv.z = 1.0f / (float)(d.z < 1 ? 1 : d.z);
        iv.w = 1.0f / (float)(d.w < 1 ? 1 : d.w);
        *(float4*)&inv_deg[base + i * 4] = iv;
        prefix = rp.w + d.w;
    }
    if (t == 255) row_ptr[N_NODES] = prefix;
}

__global__ __launch_bounds__(256) void fill_kernel(const int* __restrict__ edge,
                                                   int* __restrict__ cursor,
                                                   int* __restrict__ col) {
    int e = blockIdx.x * 256 + threadIdx.x;
    if (e < N_EDGES) {
        int pos = atomicAdd(&cursor[edge[N_EDGES + e]], 1);
        col[pos] = edge[e];
    }
}

// ---------------------------------------------------------------------------
// Mean aggregation: one wave per node; gathers HI ONLY; writes split hi/lo.
// ---------------------------------------------------------------------------
__global__ __launch_bounds__(256) void agg_kernel(const u16* __restrict__ Xhi,
                                                  const int* __restrict__ row_ptr,
                                                  const int* __restrict__ col,
                                                  const float* __restrict__ inv_deg,
                                                  u16* __restrict__ Agghi,
                                                  u16* __restrict__ Agglo) {
    int node = blockIdx.x * 4 + (threadIdx.x >> 6);
    int lane = threadIdx.x & 63;
    int start = row_ptr[node];
    int end   = row_ptr[node + 1];
    float a0 = 0.f, a1 = 0.f, a2 = 0.f, a3 = 0.f;
    for (int e0 = start; e0 < end; e0 += 64) {
        int cnt = end - e0; if (cnt > 64) cnt = 64;
        int my = (lane < cnt) ? col[e0 + lane] : 0;
        for (int j = 0; j < cnt; ++j) {
            int s = __shfl(my, j);
            u16x4 v = *(const u16x4*)&Xhi[(size_t)s * D + lane * 4];
            a0 += bf2f(v[0]); a1 += bf2f(v[1]); a2 += bf2f(v[2]); a3 += bf2f(v[3]);
        }
    }
    float id = inv_deg[node];
    float m[4] = {a0 * id, a1 * id, a2 * id, a3 * id};
    u16x4 H, L;
    #pragma unroll
    for (int j = 0; j < 4; ++j) {
        u16 h = f2bf(m[j]);
        H[j] = h; L[j] = f2bf(m[j] - bf2f(h));
    }
    *(u16x4*)&Agghi[(size_t)node * D + lane * 4] = H;
    *(u16x4*)&Agglo[(size_t)node * D + lane * 4] = L;
}

// ---------------------------------------------------------------------------
// MFMA dual GEMM, split-bf16 3-pass (unchanged from R3)
// ---------------------------------------------------------------------------
__global__ __launch_bounds__(256) void gemm_mfma_kernel(
    const u16* __restrict__ Xhi,   const u16* __restrict__ Xlo,
    const u16* __restrict__ Agghi, const u16* __restrict__ Agglo,
    const u16* __restrict__ WtRhi, const u16* __restrict__ WtRlo,
    const u16* __restrict__ WtLhi, const u16* __restrict__ WtLlo,
    const float* __restrict__ bias,
    u16* __restrict__ Xohi, u16* __restrict__ Xolo)
{
    __shared__ u16 lds[2][4][4096];   // [buf][Ahi,Alo,Bhi,Blo][8KB]

    const int tid  = threadIdx.x;
    const int w    = tid >> 6, lane = tid & 63;
    const int wm   = w >> 1, wn = w & 1;
    const int bid  = blockIdx.x;
    const int m0   = (bid >> 1) * 128;
    const int n0   = (bid & 1) * 128;

    f32x16 acc[4];
    #pragma unroll
    for (int f = 0; f < 4; ++f)
        #pragma unroll
        for (int j = 0; j < 16; ++j) acc[f][j] = 0.f;

    const int r32 = lane & 31;
    const int khb = (lane >> 5) * 16;

    auto stage = [&](int buf, int tt) {
        const u16* src; int rbase;
        const int k0 = (tt & 7) * 32;
        const bool ph2 = tt >= 8;
        if      (w == 0) { src = ph2 ? Agghi : Xhi;  rbase = m0; }
        else if (w == 1) { src = ph2 ? Agglo : Xlo;  rbase = m0; }
        else if (w == 2) { src = ph2 ? WtLhi : WtRhi; rbase = n0; }
        else             { src = ph2 ? WtLlo : WtRlo; rbase = n0; }
        char* base = (char*)&lds[buf][w][0];
        #pragma unroll
        for (int i = 0; i < 8; ++i) {
            int o = i * 1024 + lane * 16;
            int a = swz(o);
            const u16* g = src + (size_t)(rbase + (a >> 6)) * D + k0 + ((a & 63) >> 1);
            gload16(g, base + i * 1024);
        }
    };

    auto compute = [&](int buf) {
        const char* Ah = (const char*)&lds[buf][0][0];
        const char* Al = (const char*)&lds[buf][1][0];
        const char* Bh = (const char*)&lds[buf][2][0];
        const char* Bl = (const char*)&lds[buf][3][0];
        #pragma unroll
        for (int s = 0; s < 2; ++s) {
            const int cb = s * 32 + khb;
            const int ra0 = wm * 64 + r32, ra1 = ra0 + 32;
            const int rb0 = wn * 64 + r32, rb1 = rb0 + 32;
            bf16x8 ah0 = *(const bf16x8*)(Ah + swz(ra0 * 64 + cb));
            bf16x8 ah1 = *(const bf16x8*)(Ah + swz(ra1 * 64 + cb));
            bf16x8 al0 = *(const bf16x8*)(Al + swz(ra0 * 64 + cb));
            bf16x8 al1 = *(const bf16x8*)(Al + swz(ra1 * 64 + cb));
            bf16x8 bh0 = *(const bf16x8*)(Bh + swz(rb0 * 64 + cb));
            bf16x8 bh1 = *(const bf16x8*)(Bh + swz(rb1 * 64 + cb));
            bf16x8 bl0 = *(const bf16x8*)(Bl + swz(rb0 * 64 + cb));
            bf16x8 bl1 = *(const bf16x8*)(Bl + swz(rb1 * 64 + cb));
            acc[0] = __builtin_amdgcn_mfma_f32_32x32x16_bf16(ah0, bh0, acc[0], 0, 0, 0);
            acc[1] = __builtin_amdgcn_mfma_f32_32x32x16_bf16(ah0, bh1, acc[1], 0, 0, 0);
            acc[2] = __builtin_amdgcn_mfma_f32_32x32x16_bf16(ah1, bh0, acc[2], 0, 0, 0);
            acc[3] = __builtin_amdgcn_mfma_f32_32x32x16_bf16(ah1, bh1, acc[3], 0, 0, 0);
            acc[0] = __builtin_amdgcn_mfma_f32_32x32x16_bf16(al0, bh0, acc[0], 0, 0, 0);
            acc[1] = __builtin_amdgcn_mfma_f32_32x32x16_bf16(al0, bh1, acc[1], 0, 0, 0);
            acc[2] = __builtin_amdgcn_mfma_f32_32x32x16_bf16(al1, bh0, acc[2], 0, 0, 0);
            acc[3] = __builtin_amdgcn_mfma_f32_32x32x16_bf16(al1, bh1, acc[3], 0, 0, 0);
            acc[0] = __builtin_amdgcn_mfma_f32_32x32x16_bf16(ah0, bl0, acc[0], 0, 0, 0);
            acc[1] = __builtin_amdgcn_mfma_f32_32x32x16_bf16(ah0, bl1, acc[1], 0, 0, 0);
            acc[2] = __builtin_amdgcn_mfma_f32_32x32x16_bf16(ah1, bl0, acc[2], 0, 0, 0);
            acc[3] = __builtin_amdgcn_mfma_f32_32x32x16_bf16(ah1, bl1, acc[3], 0, 0, 0);
        }
    };

    stage(0, 0);
    __syncthreads();
    int cur = 0;
    for (int t = 0; t < 16; ++t) {
        if (t < 15) stage(cur ^ 1, t + 1);
        compute(cur);
        __syncthreads();
        cur ^= 1;
    }

    #pragma unroll
    for (int fm = 0; fm < 2; ++fm) {
        #pragma unroll
        for (int fn = 0; fn < 2; ++fn) {
            const int colc = n0 + wn * 64 + fn * 32 + r32;
            const int rowb = m0 + wm * 64 + fm * 32 + 4 * (lane >> 5);
            const float bv = bias[colc];
            #pragma unroll
            for (int reg = 0; reg < 16; ++reg) {
                const int row = rowb + (reg & 3) + 8 * (reg >> 2);
                float v = acc[fm * 2 + fn][reg] + bv;
                u16 h = f2bf(v);
                Xohi[(size_t)row * D + colc] = h;
                Xolo[(size_t)row * D + colc] = f2bf(v - bf2f(h));
            }
        }
    }
}

// ---------------------------------------------------------------------------
// MLP head v3: 32 blocks (one per graph) x 1024 threads.
// Thread (c = t&255, kq = t>>8): partial dot over 64 k's, 8 loads in flight,
// then 4-way LDS reduce. 3 chained layers.
// ---------------------------------------------------------------------------
__global__ __launch_bounds__(1024) void head_kernel(const u16* __restrict__ Xhi,
                                                    const u16* __restrict__ Xlo,
                                                    const float* __restrict__ Wh,
                                                    const float* __restrict__ bh,
                                                    const float* __restrict__ Wo,
                                                    const float* __restrict__ bo,
                                                    float* __restrict__ out) {
    __shared__ float h[D];
    __shared__ float part[4][D];
    const int b = blockIdx.x, t = threadIdx.x;
    if (t < D) {
        size_t idx = (size_t)(b * NODES_PER_GRAPH) * D + t;
        h[t] = bf2f(Xhi[idx]) + bf2f(Xlo[idx]);
    }
    __syncthreads();
    const int c = t & 255, kq = t >> 8;
    for (int l = 0; l < 3; ++l) {
        const float* W = (l < 2) ? Wh + (size_t)l * D * D : Wo;
        float acc = 0.f;
        #pragma unroll
        for (int k0 = 0; k0 < 64; k0 += 8) {
            float wv[8];
            #pragma unroll
            for (int j = 0; j < 8; ++j)
                wv[j] = W[(size_t)(kq * 64 + k0 + j) * D + c];
            #pragma unroll
            for (int j = 0; j < 8; ++j)
                acc += h[kq * 64 + k0 + j] * wv[j];
        }
        part[kq][c] = acc;
        __syncthreads();
        if (t < D) {
            float v = part[0][t] + part[1][t] + part[2][t] + part[3][t]
                    + ((l < 2) ? bh[(size_t)l * D + t] : bo[t]);
            if (l < 2) h[t] = fmaxf(v, 0.f);
            else       out[(size_t)b * D + t] = v;
        }
        __syncthreads();
    }
}

// ---------------------------------------------------------------------------
extern "C" void kernel_launch(void* const* d_in, const int* in_sizes, int n_in,
                              void* d_out, int out_size, void* d_ws, size_t ws_size,
                              hipStream_t stream) {
    const float* x    = (const float*)d_in[0];
    const int*   edge = (const int*)d_in[1];
    const float* Wl   = (const float*)d_in[2];
    const float* bl   = (const float*)d_in[3];
    const float* Wr   = (const float*)d_in[4];
    const float* Wh   = (const float*)d_in[5];
    const float* bh   = (const float*)d_in[6];
    const float* Wo   = (const float*)d_in[7];
    const float* bo   = (const float*)d_in[8];
    float* out = (float*)d_out;

    char* w = (char*)d_ws;
    auto alloc = [&](size_t bytes) {
        char* p = w;
        w += (bytes + 255) & ~(size_t)255;
        return p;
    };
    int*   deg     = (int*)  alloc((size_t)N_NODES * 4);
    int*   row_ptr = (int*)  alloc((size_t)(N_NODES + 1) * 4);
    int*   cursor  = (int*)  alloc((size_t)N_NODES * 4);
    float* invdeg  = (float*)alloc((size_t)N_NODES * 4);
    int*   col     = (int*)  alloc((size_t)N_EDGES * 4);
    u16* Xh[2] = {(u16*)alloc((size_t)N_NODES * D * 2), (u16*)alloc((size_t)N_NODES * D * 2)};
    u16* Xl[2] = {(u16*)alloc((size_t)N_NODES * D * 2), (u16*)alloc((size_t)N_NODES * D * 2)};
    u16* Agghi = (u16*)alloc((size_t)N_NODES * D * 2);
    u16* Agglo = (u16*)alloc((size_t)N_NODES * D * 2);
    u16* WtLhi = (u16*)alloc((size_t)3 * 65536 * 2);
    u16* WtLlo = (u16*)alloc((size_t)3 * 65536 * 2);
    u16* WtRhi = (u16*)alloc((size_t)3 * 65536 * 2);
    u16* WtRlo = (u16*)alloc((size_t)3 * 65536 * 2);

    prep_kernel<<<2208, 256, 0, stream>>>(x, Wl, Wr, Xh[0], Xl[0],
                                          WtLhi, WtLlo, WtRhi, WtRlo, deg);
    count_deg_kernel<<<N_EDGES / 256, 256, 0, stream>>>(edge, deg);
    scan_kernel<<<1, 256, 0, stream>>>(deg, row_ptr, cursor, invdeg);
    fill_kernel<<<N_EDGES / 256, 256, 0, stream>>>(edge, cursor, col);

    for (int l = 0; l < 3; ++l) {
        int in = l & 1, o = in ^ 1;
        agg_kernel<<<N_NODES / 4, 256, 0, stream>>>(Xh[in], row_ptr, col, invdeg,
                                                    Agghi, Agglo);
        gemm_mfma_kernel<<<256, 256, 0, stream>>>(
            Xh[in], Xl[in], Agghi, Agglo,
            WtRhi + (size_t)l * 65536, WtRlo + (size_t)l * 65536,
            WtLhi + (size_t)l * 65536, WtLlo + (size_t)l * 65536,
            bl + (size_t)l * D, Xh[o], Xl[o]);
    }
    head_kernel<<<B_GRAPHS, 1024, 0, stream>>>(Xh[1], Xl[1], Wh, bh, Wo, bo, out);
}